// Round 11
// baseline (109.721 us; speedup 1.0000x reference)
//
#include <hip/hip_runtime.h>

#define NN 4096
#define DD 512
#define TT 4096

typedef __bf16 bf16x8 __attribute__((ext_vector_type(8)));
typedef float f32x4 __attribute__((ext_vector_type(4)));

constexpr float INV_TEMP = 1.0f / 0.07f;

#define AS1(p) ((__attribute__((address_space(1))) const void*)(p))
#define AS3(p) ((__attribute__((address_space(3))) void*)(p))

// ---------------- normalize (fp32 -> normalized bf16) + triplet + counter zero ----------------
__global__ __launch_bounds__(256) void k_normtrip(const float* __restrict__ emb,
                                                  __bf16* __restrict__ nemb,
                                                  const int* __restrict__ trip,
                                                  float* __restrict__ tl,
                                                  int* __restrict__ counter) {
    int wave = threadIdx.x >> 6, lane = threadIdx.x & 63;
    int row = blockIdx.x * 4 + wave;

    // re-zero the rowfinal ticket counter every iteration (ws is poisoned by the harness)
    if (blockIdx.x == 0 && threadIdx.x == 0) *counter = 0;

    // ---- triplet gathers (issue early, reduce late) ----
    int ia = trip[row * 3 + 0], ip = trip[row * 3 + 1], ig = trip[row * 3 + 2];
    const float4* pa = (const float4*)(emb + (size_t)ia * DD);
    const float4* pp = (const float4*)(emb + (size_t)ip * DD);
    const float4* pn = (const float4*)(emb + (size_t)ig * DD);
    float d1 = 0.0f, d2 = 0.0f;
    #pragma unroll
    for (int j = 0; j < 2; ++j) {
        float4 a = pa[lane * 2 + j];
        float4 p = pp[lane * 2 + j];
        float4 n = pn[lane * 2 + j];
        float dx;
        dx = a.x - p.x + 1e-6f; d1 += dx * dx;
        dx = a.y - p.y + 1e-6f; d1 += dx * dx;
        dx = a.z - p.z + 1e-6f; d1 += dx * dx;
        dx = a.w - p.w + 1e-6f; d1 += dx * dx;
        dx = a.x - n.x + 1e-6f; d2 += dx * dx;
        dx = a.y - n.y + 1e-6f; d2 += dx * dx;
        dx = a.z - n.z + 1e-6f; d2 += dx * dx;
        dx = a.w - n.w + 1e-6f; d2 += dx * dx;
    }

    // ---- normalize ----
    const float4* src = (const float4*)(emb + (size_t)row * DD);
    float4 x0 = src[lane * 2 + 0];
    float4 x1 = src[lane * 2 + 1];
    float ss = x0.x * x0.x + x0.y * x0.y + x0.z * x0.z + x0.w * x0.w +
               x1.x * x1.x + x1.y * x1.y + x1.z * x1.z + x1.w * x1.w;
    #pragma unroll
    for (int m = 1; m < 64; m <<= 1) ss += __shfl_xor(ss, m, 64);
    float inv = 1.0f / fmaxf(sqrtf(ss), 1e-8f);
    bf16x8 v;
    v[0] = (__bf16)(x0.x * inv); v[1] = (__bf16)(x0.y * inv);
    v[2] = (__bf16)(x0.z * inv); v[3] = (__bf16)(x0.w * inv);
    v[4] = (__bf16)(x1.x * inv); v[5] = (__bf16)(x1.y * inv);
    v[6] = (__bf16)(x1.z * inv); v[7] = (__bf16)(x1.w * inv);
    *(bf16x8*)(nemb + (size_t)row * DD + lane * 8) = v;

    // ---- triplet reduce + store ----
    #pragma unroll
    for (int m = 1; m < 64; m <<= 1) {
        d1 += __shfl_xor(d1, m, 64);
        d2 += __shfl_xor(d2, m, 64);
    }
    if (lane == 0) tl[row] = fmaxf(sqrtf(d1) - sqrtf(d2) + 0.5f, 0.0f);
}

// ---------------- contrast: symmetric triangle, 128x128 tiles COL-SPLIT x2, full K ----------
// Verified round 10 (95.6us total, absmax 0): triangular tiles split into two 128x64 column
// halves with full K=512 (output-space split only — K-split is invalid, exp is nonlinear).
// 128-thread blocks, 25KB single-buffer LDS -> 6 blocks/CU for deep cross-block TLP (the
// one overlap mechanism measured to work this session). 1056 blocks: makespan ~1.21x ideal.
// Slot algebra (64 slots/row, each written exactly once, plain stores, no float atomics):
//   rows of block b: row-sums from (b, c>=b, ch) at slot 2c+ch   -> [2b, 64)
//                    col-sums from (r<b, b, ch)  at slot 2r+wave -> [0, 2b)
// Zero-conflict XOR swizzle pair (SQ_LDS_BANK_CONFLICT=0, rounds 6-10); gload_lds width 16.

__global__ __launch_bounds__(128, 3) void k_contrast(const __bf16* __restrict__ nemb,
                                                     const int* __restrict__ labels,
                                                     float* __restrict__ posP,
                                                     float* __restrict__ totP) {
    __shared__ __attribute__((aligned(16))) __bf16 aS[128 * 64];
    __shared__ __attribute__((aligned(16))) __bf16 bS[64 * 64];
    __shared__ int rlab[128];
    __shared__ int clab[64];

    int tid = threadIdx.x;
    int lane = tid & 63, wave = tid >> 6;     // 2 waves; wave owns rows [wave*64, +64)
    int l15 = lane & 15, quad = lane >> 4;
    int swz = l15 & 7;

    // XCD chunk map (1056 = 8*132, bijective); u = 2*t + ch keeps both col-halves of a
    // tile on the same XCD. Triangular decode t -> (r,c), r<=c<32.
    int u = (blockIdx.x & 7) * 132 + (blockIdx.x >> 3);
    int t = u >> 1, ch = u & 1;
    int r = 0;
    while (t >= 32 - r) { t -= 32 - r; ++r; }
    int c = r + t;
    int row0 = r * 128, col0 = c * 128;
    int cb0 = col0 + ch * 64;                 // this block's 64-column window

    rlab[tid] = labels[row0 + tid];
    if (tid < 64) clab[tid] = labels[cb0 + tid];

    // staging: thread covers row (tid>>3) (+16 per issue), 16B chunk (tid&7); SOURCE chunk
    // pre-swizzled by row&7 (involution with the swizzled ds_read — verified zero-conflict).
    int srr = (tid >> 3) & 7;
    int scol = ((tid & 7) ^ srr) * 8;
    const __bf16* gA0 = nemb + (size_t)(row0 + (tid >> 3)) * DD + scol;
    const __bf16* gB0 = nemb + (size_t)(cb0 + (tid >> 3)) * DD + scol;
    int ldst = tid * 8;

    f32x4 acc[4][4];
    #pragma unroll
    for (int fm = 0; fm < 4; ++fm)
        #pragma unroll
        for (int fn = 0; fn < 4; ++fn) {
            f32x4 z = {0.0f, 0.0f, 0.0f, 0.0f};
            acc[fm][fn] = z;
        }

    #pragma unroll
    for (int kt = 0; kt < 8; ++kt) {
        #pragma unroll
        for (int j = 0; j < 8; ++j)
            __builtin_amdgcn_global_load_lds(AS1(gA0 + (size_t)(j * 16) * DD + kt * 64),
                                             AS3(&aS[ldst + j * 1024]), 16, 0, 0);
        #pragma unroll
        for (int j = 0; j < 4; ++j)
            __builtin_amdgcn_global_load_lds(AS1(gB0 + (size_t)(j * 16) * DD + kt * 64),
                                             AS3(&bS[ldst + j * 1024]), 16, 0, 0);
        __syncthreads();   // drains vmcnt(0): tile resident for both waves
        #pragma unroll
        for (int kc = 0; kc < 2; ++kc) {
            bf16x8 af[4], bf[4];
            #pragma unroll
            for (int fm = 0; fm < 4; ++fm)
                af[fm] = *(const bf16x8*)(&aS[(wave * 64 + fm * 16 + l15) * 64 +
                                              (((kc * 4 + quad) ^ swz) * 8)]);
            #pragma unroll
            for (int fn = 0; fn < 4; ++fn)
                bf[fn] = *(const bf16x8*)(&bS[(fn * 16 + l15) * 64 +
                                              (((kc * 4 + quad) ^ swz) * 8)]);
            #pragma unroll
            for (int fm = 0; fm < 4; ++fm)
                #pragma unroll
                for (int fn = 0; fn < 4; ++fn)
                    acc[fm][fn] = __builtin_amdgcn_mfma_f32_16x16x32_bf16(
                        af[fm], bf[fn], acc[fm][fn], 0, 0, 0);
        }
        if (kt < 7) __syncthreads();   // WAR: all reads done before next stage overwrites
    }

    // ---- epilogue: row-sums (always) + col-sums (off-diag), plain stores ----
    float tc[4] = {0, 0, 0, 0}, pc[4] = {0, 0, 0, 0};   // per-fn column accumulators
    #pragma unroll
    for (int fm = 0; fm < 4; ++fm) {
        int rloc = wave * 64 + fm * 16 + quad * 4;
        int gibase = row0 + rloc;
        int rl[4];
        #pragma unroll
        for (int v = 0; v < 4; ++v) rl[v] = rlab[rloc + v];
        float tv[4] = {0, 0, 0, 0}, pv[4] = {0, 0, 0, 0};
        #pragma unroll
        for (int fn = 0; fn < 4; ++fn) {
            int cloc = fn * 16 + l15;
            int cl = clab[cloc];
            int gj = cb0 + cloc;
            f32x4 a = acc[fm][fn];
            #pragma unroll
            for (int v = 0; v < 4; ++v) {
                float e = __expf(a[v] * INV_TEMP);
                tv[v] += e;
                bool match = (rl[v] == cl) && ((gibase + v) != gj);
                float pe = match ? e : 0.0f;
                pv[v] += pe;
                tc[fn] += e;
                pc[fn] += pe;
            }
        }
        #pragma unroll
        for (int m = 1; m < 16; m <<= 1) {
            #pragma unroll
            for (int v = 0; v < 4; ++v) {
                tv[v] += __shfl_xor(tv[v], m, 64);
                pv[v] += __shfl_xor(pv[v], m, 64);
            }
        }
        if (l15 == 0) {
            #pragma unroll
            for (int v = 0; v < 4; ++v) {
                int o = (gibase + v) * 64 + c * 2 + ch;   // row-sum slot: 2c+ch
                posP[o] = pv[v];
                totP[o] = tv[v];
            }
        }
    }

    if (r != c) {
        // reduce column accumulators over quad (lanes sharing l15): xor 16, 32
        #pragma unroll
        for (int fn = 0; fn < 4; ++fn) {
            tc[fn] += __shfl_xor(tc[fn], 16, 64);
            tc[fn] += __shfl_xor(tc[fn], 32, 64);
            pc[fn] += __shfl_xor(pc[fn], 16, 64);
            pc[fn] += __shfl_xor(pc[fn], 32, 64);
        }
        if (quad == 0) {
            #pragma unroll
            for (int fn = 0; fn < 4; ++fn) {
                int gcol = cb0 + fn * 16 + l15;
                int o = gcol * 64 + r * 2 + wave;         // col-sum slot: 2r+wave
                posP[o] = pc[fn];
                totP[o] = tc[fn];
            }
        }
    }
}

// ---------------- per-row loss + final reduce (fused via last-block reduction) ----------
// Validity: pos_mask row-sum > 0 <=> label multiplicity > 1 (labels in [0,256)).
// Each of 1024 blocks handles 4 rows (wave per row), writes one (sl,sv,st) partial,
// device-scope fence, int atomicAdd ticket (native instr — NOT float CAS, round-4 lesson).
// Last block re-fences (acquire) and reduces the 1024 partials to out[0..2].
__global__ __launch_bounds__(256) void k_rowfinal(const float* __restrict__ posP,
                                                  const float* __restrict__ totP,
                                                  const int* __restrict__ labels,
                                                  const float* __restrict__ tl,
                                                  float* __restrict__ part,
                                                  int* __restrict__ counter,
                                                  float* __restrict__ out) {
    __shared__ int hist[256];
    __shared__ float red[3][4];
    __shared__ int isLast;
    int tid = threadIdx.x;
    hist[tid] = 0;
    __syncthreads();
    #pragma unroll
    for (int j = 0; j < 16; ++j)
        atomicAdd(&hist[labels[tid + j * 256]], 1);
    __syncthreads();

    int wave = tid >> 6, lane = tid & 63;
    int row = blockIdx.x * 4 + wave;
    float p = posP[row * 64 + lane];
    float t = totP[row * 64 + lane];
    #pragma unroll
    for (int m = 1; m < 64; m <<= 1) {
        p += __shfl_xor(p, m, 64);
        t += __shfl_xor(t, m, 64);
    }
    if (lane == 0) {
        bool valid = hist[labels[row]] > 1;   // counts self; >1 => a positive exists
        float loss = valid ? -logf(p / (t + 1e-8f) + 1e-8f) : 0.0f;
        red[0][wave] = loss;
        red[1][wave] = valid ? 1.0f : 0.0f;
        red[2][wave] = tl[row];
    }
    __syncthreads();
    if (tid == 0) {
        part[blockIdx.x]        = red[0][0] + red[0][1] + red[0][2] + red[0][3];
        part[1024 + blockIdx.x] = red[1][0] + red[1][1] + red[1][2] + red[1][3];
        part[2048 + blockIdx.x] = red[2][0] + red[2][1] + red[2][2] + red[2][3];
        __threadfence();                      // release partials (device scope, cross-XCD)
        isLast = (atomicAdd(counter, 1) == 1023);
    }
    __syncthreads();
    if (isLast) {
        __threadfence();                      // acquire all partials
        float sl = 0.0f, sv = 0.0f, st = 0.0f;
        #pragma unroll
        for (int j = 0; j < 4; ++j) {
            int i = tid + j * 256;
            sl += part[i];
            sv += part[1024 + i];
            st += part[2048 + i];
        }
        #pragma unroll
        for (int m = 1; m < 64; m <<= 1) {
            sl += __shfl_xor(sl, m, 64);
            sv += __shfl_xor(sv, m, 64);
            st += __shfl_xor(st, m, 64);
        }
        __syncthreads();                      // red[] reuse: prior writes consumed
        if (lane == 0) { red[0][wave] = sl; red[1][wave] = sv; red[2][wave] = st; }
        __syncthreads();
        if (tid == 0) {
            float SL = red[0][0] + red[0][1] + red[0][2] + red[0][3];
            float SV = red[1][0] + red[1][1] + red[1][2] + red[1][3];
            float ST = red[2][0] + red[2][1] + red[2][2] + red[2][3];
            float cont = (SV > 0.0f) ? (SL / SV) : 0.0f;
            float trip = ST * (1.0f / (float)TT);
            out[0] = cont + 0.3f * trip;
            out[1] = cont;
            out[2] = trip;
        }
    }
}

extern "C" void kernel_launch(void* const* d_in, const int* in_sizes, int n_in,
                              void* d_out, int out_size, void* d_ws, size_t ws_size,
                              hipStream_t stream) {
    const float* emb = (const float*)d_in[0];
    const int* labels = (const int*)d_in[1];
    const int* trips = (const int*)d_in[2];
    float* out = (float*)d_out;
    char* ws = (char*)d_ws;

    __bf16* nemb  = (__bf16*)(ws);                 // 4096*512*2 = 4194304 B
    float* posP   = (float*)(ws + 4194304);        // 4096*64*4  = 1048576 B
    float* totP   = (float*)(ws + 5242880);        // 1048576 B
    float* tl     = (float*)(ws + 6291456);        // 16384 B
    float* part   = (float*)(ws + 6307840);        // 3*1024*4 = 12288 B
    int*   counter= (int*)  (ws + 6320128);        // 4 B

    k_normtrip<<<NN / 4, 256, 0, stream>>>(emb, nemb, trips, tl, counter);
    k_contrast<<<1056, 128, 0, stream>>>(nemb, labels, posP, totP);
    k_rowfinal<<<NN / 4, 256, 0, stream>>>(posP, totP, labels, tl, part, counter, out);
}

// Round 12
// 94.487 us; speedup vs baseline: 1.1612x; 1.1612x over previous
//
#include <hip/hip_runtime.h>

#define NN 4096
#define DD 512
#define TT 4096

typedef __bf16 bf16x8 __attribute__((ext_vector_type(8)));
typedef float f32x4 __attribute__((ext_vector_type(4)));

constexpr float INV_TEMP = 1.0f / 0.07f;

#define AS1(p) ((__attribute__((address_space(1))) const void*)(p))
#define AS3(p) ((__attribute__((address_space(3))) void*)(p))

// ---------------- normalize (fp32 -> normalized bf16) + triplet, fused ----------------
__global__ __launch_bounds__(256) void k_normtrip(const float* __restrict__ emb,
                                                  __bf16* __restrict__ nemb,
                                                  const int* __restrict__ trip,
                                                  float* __restrict__ tl) {
    int wave = threadIdx.x >> 6, lane = threadIdx.x & 63;
    int row = blockIdx.x * 4 + wave;

    // ---- triplet gathers (issue early, reduce late) ----
    int ia = trip[row * 3 + 0], ip = trip[row * 3 + 1], ig = trip[row * 3 + 2];
    const float4* pa = (const float4*)(emb + (size_t)ia * DD);
    const float4* pp = (const float4*)(emb + (size_t)ip * DD);
    const float4* pn = (const float4*)(emb + (size_t)ig * DD);
    float d1 = 0.0f, d2 = 0.0f;
    #pragma unroll
    for (int j = 0; j < 2; ++j) {
        float4 a = pa[lane * 2 + j];
        float4 p = pp[lane * 2 + j];
        float4 n = pn[lane * 2 + j];
        float dx;
        dx = a.x - p.x + 1e-6f; d1 += dx * dx;
        dx = a.y - p.y + 1e-6f; d1 += dx * dx;
        dx = a.z - p.z + 1e-6f; d1 += dx * dx;
        dx = a.w - p.w + 1e-6f; d1 += dx * dx;
        dx = a.x - n.x + 1e-6f; d2 += dx * dx;
        dx = a.y - n.y + 1e-6f; d2 += dx * dx;
        dx = a.z - n.z + 1e-6f; d2 += dx * dx;
        dx = a.w - n.w + 1e-6f; d2 += dx * dx;
    }

    // ---- normalize ----
    const float4* src = (const float4*)(emb + (size_t)row * DD);
    float4 x0 = src[lane * 2 + 0];
    float4 x1 = src[lane * 2 + 1];
    float ss = x0.x * x0.x + x0.y * x0.y + x0.z * x0.z + x0.w * x0.w +
               x1.x * x1.x + x1.y * x1.y + x1.z * x1.z + x1.w * x1.w;
    #pragma unroll
    for (int m = 1; m < 64; m <<= 1) ss += __shfl_xor(ss, m, 64);
    float inv = 1.0f / fmaxf(sqrtf(ss), 1e-8f);
    bf16x8 v;
    v[0] = (__bf16)(x0.x * inv); v[1] = (__bf16)(x0.y * inv);
    v[2] = (__bf16)(x0.z * inv); v[3] = (__bf16)(x0.w * inv);
    v[4] = (__bf16)(x1.x * inv); v[5] = (__bf16)(x1.y * inv);
    v[6] = (__bf16)(x1.z * inv); v[7] = (__bf16)(x1.w * inv);
    *(bf16x8*)(nemb + (size_t)row * DD + lane * 8) = v;

    // ---- triplet reduce + store ----
    #pragma unroll
    for (int m = 1; m < 64; m <<= 1) {
        d1 += __shfl_xor(d1, m, 64);
        d2 += __shfl_xor(d2, m, 64);
    }
    if (lane == 0) tl[row] = fmaxf(sqrtf(d1) - sqrtf(d2) + 0.5f, 0.0f);
}

// ---------------- contrast: symmetric triangle, 128x128 tiles COL-SPLIT x2, full K ----------
// Verified round 10 (95.6us total, absmax 0): triangular tiles split into two 128x64 column
// halves with full K=512 (output-space split only — K-split is invalid, exp is nonlinear).
// 128-thread blocks, 25KB single-buffer LDS -> 6 blocks/CU for deep cross-block TLP (the
// one overlap mechanism measured to work this session). 1056 blocks: makespan ~1.21x ideal.
// Slot algebra (64 slots/row, each written exactly once, plain stores, no float atomics):
//   rows of block b: row-sums from (b, c>=b, ch) at slot 2c+ch   -> [2b, 64)
//                    col-sums from (r<b, b, ch)  at slot 2r+wave -> [0, 2b)
// Zero-conflict XOR swizzle pair (SQ_LDS_BANK_CONFLICT=0, rounds 6-10); gload_lds width 16.
// Round-11 lesson: last-block-reduction fusion (device threadfence x1024 + ticket atomic)
// REGRESSED +14us — a separate tiny kernel launch is cheaper than cross-XCD fence
// choreography. Keep the 4-kernel pipeline.

__global__ __launch_bounds__(128, 3) void k_contrast(const __bf16* __restrict__ nemb,
                                                     const int* __restrict__ labels,
                                                     float* __restrict__ posP,
                                                     float* __restrict__ totP) {
    __shared__ __attribute__((aligned(16))) __bf16 aS[128 * 64];
    __shared__ __attribute__((aligned(16))) __bf16 bS[64 * 64];
    __shared__ int rlab[128];
    __shared__ int clab[64];

    int tid = threadIdx.x;
    int lane = tid & 63, wave = tid >> 6;     // 2 waves; wave owns rows [wave*64, +64)
    int l15 = lane & 15, quad = lane >> 4;
    int swz = l15 & 7;

    // XCD chunk map (1056 = 8*132, bijective); u = 2*t + ch keeps both col-halves of a
    // tile on the same XCD. Triangular decode t -> (r,c), r<=c<32.
    int u = (blockIdx.x & 7) * 132 + (blockIdx.x >> 3);
    int t = u >> 1, ch = u & 1;
    int r = 0;
    while (t >= 32 - r) { t -= 32 - r; ++r; }
    int c = r + t;
    int row0 = r * 128, col0 = c * 128;
    int cb0 = col0 + ch * 64;                 // this block's 64-column window

    rlab[tid] = labels[row0 + tid];
    if (tid < 64) clab[tid] = labels[cb0 + tid];

    // staging: thread covers row (tid>>3) (+16 per issue), 16B chunk (tid&7); SOURCE chunk
    // pre-swizzled by row&7 (involution with the swizzled ds_read — verified zero-conflict).
    int srr = (tid >> 3) & 7;
    int scol = ((tid & 7) ^ srr) * 8;
    const __bf16* gA0 = nemb + (size_t)(row0 + (tid >> 3)) * DD + scol;
    const __bf16* gB0 = nemb + (size_t)(cb0 + (tid >> 3)) * DD + scol;
    int ldst = tid * 8;

    f32x4 acc[4][4];
    #pragma unroll
    for (int fm = 0; fm < 4; ++fm)
        #pragma unroll
        for (int fn = 0; fn < 4; ++fn) {
            f32x4 z = {0.0f, 0.0f, 0.0f, 0.0f};
            acc[fm][fn] = z;
        }

    #pragma unroll
    for (int kt = 0; kt < 8; ++kt) {
        #pragma unroll
        for (int j = 0; j < 8; ++j)
            __builtin_amdgcn_global_load_lds(AS1(gA0 + (size_t)(j * 16) * DD + kt * 64),
                                             AS3(&aS[ldst + j * 1024]), 16, 0, 0);
        #pragma unroll
        for (int j = 0; j < 4; ++j)
            __builtin_amdgcn_global_load_lds(AS1(gB0 + (size_t)(j * 16) * DD + kt * 64),
                                             AS3(&bS[ldst + j * 1024]), 16, 0, 0);
        __syncthreads();   // drains vmcnt(0): tile resident for both waves
        #pragma unroll
        for (int kc = 0; kc < 2; ++kc) {
            bf16x8 af[4], bf[4];
            #pragma unroll
            for (int fm = 0; fm < 4; ++fm)
                af[fm] = *(const bf16x8*)(&aS[(wave * 64 + fm * 16 + l15) * 64 +
                                              (((kc * 4 + quad) ^ swz) * 8)]);
            #pragma unroll
            for (int fn = 0; fn < 4; ++fn)
                bf[fn] = *(const bf16x8*)(&bS[(fn * 16 + l15) * 64 +
                                              (((kc * 4 + quad) ^ swz) * 8)]);
            #pragma unroll
            for (int fm = 0; fm < 4; ++fm)
                #pragma unroll
                for (int fn = 0; fn < 4; ++fn)
                    acc[fm][fn] = __builtin_amdgcn_mfma_f32_16x16x32_bf16(
                        af[fm], bf[fn], acc[fm][fn], 0, 0, 0);
        }
        if (kt < 7) __syncthreads();   // WAR: all reads done before next stage overwrites
    }

    // ---- epilogue: row-sums (always) + col-sums (off-diag), plain stores ----
    float tc[4] = {0, 0, 0, 0}, pc[4] = {0, 0, 0, 0};   // per-fn column accumulators
    #pragma unroll
    for (int fm = 0; fm < 4; ++fm) {
        int rloc = wave * 64 + fm * 16 + quad * 4;
        int gibase = row0 + rloc;
        int rl[4];
        #pragma unroll
        for (int v = 0; v < 4; ++v) rl[v] = rlab[rloc + v];
        float tv[4] = {0, 0, 0, 0}, pv[4] = {0, 0, 0, 0};
        #pragma unroll
        for (int fn = 0; fn < 4; ++fn) {
            int cloc = fn * 16 + l15;
            int cl = clab[cloc];
            int gj = cb0 + cloc;
            f32x4 a = acc[fm][fn];
            #pragma unroll
            for (int v = 0; v < 4; ++v) {
                float e = __expf(a[v] * INV_TEMP);
                tv[v] += e;
                bool match = (rl[v] == cl) && ((gibase + v) != gj);
                float pe = match ? e : 0.0f;
                pv[v] += pe;
                tc[fn] += e;
                pc[fn] += pe;
            }
        }
        #pragma unroll
        for (int m = 1; m < 16; m <<= 1) {
            #pragma unroll
            for (int v = 0; v < 4; ++v) {
                tv[v] += __shfl_xor(tv[v], m, 64);
                pv[v] += __shfl_xor(pv[v], m, 64);
            }
        }
        if (l15 == 0) {
            #pragma unroll
            for (int v = 0; v < 4; ++v) {
                int o = (gibase + v) * 64 + c * 2 + ch;   // row-sum slot: 2c+ch
                posP[o] = pv[v];
                totP[o] = tv[v];
            }
        }
    }

    if (r != c) {
        // reduce column accumulators over quad (lanes sharing l15): xor 16, 32
        #pragma unroll
        for (int fn = 0; fn < 4; ++fn) {
            tc[fn] += __shfl_xor(tc[fn], 16, 64);
            tc[fn] += __shfl_xor(tc[fn], 32, 64);
            pc[fn] += __shfl_xor(pc[fn], 16, 64);
            pc[fn] += __shfl_xor(pc[fn], 32, 64);
        }
        if (quad == 0) {
            #pragma unroll
            for (int fn = 0; fn < 4; ++fn) {
                int gcol = cb0 + fn * 16 + l15;
                int o = gcol * 64 + r * 2 + wave;         // col-sum slot: 2r+wave
                posP[o] = pc[fn];
                totP[o] = tc[fn];
            }
        }
    }
}

// ---------------- per-row loss: LDS label histogram for validity + 64-slot reduce ----------
// Validity: pos_mask row-sum > 0  <=>  label multiplicity > 1 (labels in [0,256)).
__global__ __launch_bounds__(256) void k_rowloss(const float* __restrict__ posP,
                                                 const float* __restrict__ totP,
                                                 const int* __restrict__ labels,
                                                 float* __restrict__ rloss,
                                                 float* __restrict__ rvalid) {
    __shared__ int hist[256];
    int tid = threadIdx.x;
    hist[tid] = 0;
    __syncthreads();
    #pragma unroll
    for (int j = 0; j < 16; ++j)
        atomicAdd(&hist[labels[tid + j * 256]], 1);
    __syncthreads();

    int wave = tid >> 6, lane = tid & 63;
    int row = blockIdx.x * 4 + wave;
    float p = posP[row * 64 + lane];
    float t = totP[row * 64 + lane];
    #pragma unroll
    for (int m = 1; m < 64; m <<= 1) {
        p += __shfl_xor(p, m, 64);
        t += __shfl_xor(t, m, 64);
    }
    if (lane == 0) {
        bool valid = hist[labels[row]] > 1;   // counts self; >1 => a positive exists
        float loss = valid ? -logf(p / (t + 1e-8f) + 1e-8f) : 0.0f;
        rloss[row] = loss;
        rvalid[row] = valid ? 1.0f : 0.0f;
    }
}

// ---------------- final reduction ----------------
__global__ __launch_bounds__(256) void k_final(const float* __restrict__ rloss,
                                               const float* __restrict__ rvalid,
                                               const float* __restrict__ tl,
                                               float* __restrict__ out) {
    int tid = threadIdx.x;
    float sl = 0.0f, sv = 0.0f, st = 0.0f;
    for (int i = tid; i < NN; i += 256) {
        sl += rloss[i];
        sv += rvalid[i];
        st += tl[i];
    }
    #pragma unroll
    for (int m = 1; m < 64; m <<= 1) {
        sl += __shfl_xor(sl, m, 64);
        sv += __shfl_xor(sv, m, 64);
        st += __shfl_xor(st, m, 64);
    }
    __shared__ float red[3][4];
    int lane = tid & 63, wave = tid >> 6;
    if (lane == 0) { red[0][wave] = sl; red[1][wave] = sv; red[2][wave] = st; }
    __syncthreads();
    if (tid == 0) {
        float SL = red[0][0] + red[0][1] + red[0][2] + red[0][3];
        float SV = red[1][0] + red[1][1] + red[1][2] + red[1][3];
        float ST = red[2][0] + red[2][1] + red[2][2] + red[2][3];
        float cont = (SV > 0.0f) ? (SL / SV) : 0.0f;
        float trip = ST * (1.0f / (float)TT);
        out[0] = cont + 0.3f * trip;
        out[1] = cont;
        out[2] = trip;
    }
}

extern "C" void kernel_launch(void* const* d_in, const int* in_sizes, int n_in,
                              void* d_out, int out_size, void* d_ws, size_t ws_size,
                              hipStream_t stream) {
    const float* emb = (const float*)d_in[0];
    const int* labels = (const int*)d_in[1];
    const int* trips = (const int*)d_in[2];
    float* out = (float*)d_out;
    char* ws = (char*)d_ws;

    __bf16* nemb  = (__bf16*)(ws);                 // 4096*512*2 = 4194304 B
    float* posP   = (float*)(ws + 4194304);        // 4096*64*4  = 1048576 B
    float* totP   = (float*)(ws + 5242880);        // 1048576 B
    float* rloss  = (float*)(ws + 6291456);        // 16384 B
    float* rvalid = (float*)(ws + 6307840);        // 16384 B
    float* tl     = (float*)(ws + 6324224);        // 16384 B

    k_normtrip<<<NN / 4, 256, 0, stream>>>(emb, nemb, trips, tl);
    k_contrast<<<1056, 128, 0, stream>>>(nemb, labels, posP, totP);
    k_rowloss<<<NN / 4, 256, 0, stream>>>(posP, totP, labels, rloss, rvalid);
    k_final<<<1, 256, 0, stream>>>(rloss, rvalid, tl, out);
}